// Round 2
// baseline (83.190 us; speedup 1.0000x reference)
//
#include <hip/hip_runtime.h>
#include <cstdint>
#include <cstddef>
#include <math.h>

#define B 16
#define S 200
#define D 128
#define VOCAB 100000
#define SCH 8
#define GEMV_BLOCKS ((VOCAB + 255) / 256)   // 391

// K1: attention scores: per block = one (b, chunk of 8 s). 128 threads (one per e-dim).
__global__ __launch_bounds__(128) void k_scores(
    const float* __restrict__ x,
    const float* __restrict__ Wq, const float* __restrict__ bq,
    const float* __restrict__ Wk, const float* __restrict__ bk,
    const float* __restrict__ Wv, const float* __restrict__ bv,
    float* __restrict__ scores)
{
  const int b  = blockIdx.x / (S / SCH);
  const int s0 = (blockIdx.x % (S / SCH)) * SCH;
  const int e  = threadIdx.x;

  __shared__ float lx[SCH][D];
  __shared__ float l0[D];
  __shared__ float sred[2][SCH];

  l0[e] = x[(size_t)b * S * D + e];
  #pragma unroll
  for (int i = 0; i < SCH; i++) lx[i][e] = x[((size_t)b * S + s0 + i) * D + e];
  __syncthreads();

  float q[SCH];
  const float bqe = bq[e];
  #pragma unroll
  for (int i = 0; i < SCH; i++) q[i] = bqe;
  float kk = bk[e];

  for (int d = 0; d < D; d++) {
    const float wq = Wq[d * D + e];
    const float wk = Wk[d * D + e];
    const float x0 = l0[d];
    kk += x0 * wk;
    #pragma unroll
    for (int i = 0; i < SCH; i++) q[i] += lx[i][d] * wq;
  }

  const float wv  = Wv[e];
  const float bv0 = bv[0];
  #pragma unroll
  for (int i = 0; i < SCH; i++) {
    float val = tanhf(q[i] + kk) * wv;
    #pragma unroll
    for (int off = 32; off > 0; off >>= 1) val += __shfl_down(val, off, 64);
    if ((e & 63) == 0) sred[e >> 6][i] = val;
  }
  __syncthreads();
  if (e < SCH) scores[b * S + s0 + e] = sred[0][e] + sred[1][e] + bv0;
}

// K2: softmax over S + c_s; writes cvec[dd*16 + b], dd 0..255 (h_t | c_s).
__global__ __launch_bounds__(256) void k_csum(
    const float* __restrict__ x, const float* __restrict__ scores,
    float* __restrict__ cvec)
{
  const int b = blockIdx.x;
  const int t = threadIdx.x;
  __shared__ float pr[S];
  __shared__ float red[8];
  __shared__ float cpart[D];

  float v = (t < S) ? scores[b * S + t] : -INFINITY;
  float m = v;
  #pragma unroll
  for (int off = 32; off > 0; off >>= 1) m = fmaxf(m, __shfl_down(m, off, 64));
  if ((t & 63) == 0) red[t >> 6] = m;
  __syncthreads();
  if (t == 0) red[4] = fmaxf(fmaxf(red[0], red[1]), fmaxf(red[2], red[3]));
  __syncthreads();
  const float mx = red[4];

  float e = (t < S) ? expf(v - mx) : 0.f;
  float s = e;
  #pragma unroll
  for (int off = 32; off > 0; off >>= 1) s += __shfl_down(s, off, 64);
  if ((t & 63) == 0) red[t >> 6] = s;
  __syncthreads();
  if (t == 0) red[5] = red[0] + red[1] + red[2] + red[3];
  __syncthreads();
  const float inv = 1.0f / red[5];
  if (t < S) pr[t] = e * inv;
  __syncthreads();

  // c_s: thread t -> d = t&127, s-half = t>>7 (100 s each), combine halves.
  const int d = t & 127;
  const int h = t >> 7;
  float acc = 0.f;
  const float* xb = x + ((size_t)b * S + h * 100) * D + d;
  #pragma unroll 4
  for (int s2 = 0; s2 < 100; s2++) acc += pr[h * 100 + s2] * xb[s2 * D];
  if (h) cpart[d] = acc;
  __syncthreads();
  if (!h) {
    cvec[d * B + b]       = x[(size_t)b * S * D + d];   // h_t (dims 0..127)
    cvec[(D + d) * B + b] = acc + cpart[d];             // c_s (dims 128..255)
  }
}

// K3: fused gemv + bias + exp + per-block partial sums.
// One thread per vocab column v; c read with wave-uniform indices (scalar loads).
__global__ __launch_bounds__(256) void k_gemv(
    const float* __restrict__ cvec, const float* __restrict__ Wec,
    const float* __restrict__ bec, float* __restrict__ out,
    float* __restrict__ partial)
{
  const int t = threadIdx.x;
  const int v = blockIdx.x * 256 + t;
  __shared__ float lred[4][16];

  float acc[16];
  #pragma unroll
  for (int bb = 0; bb < 16; bb++) acc[bb] = 0.f;

  if (v < VOCAB) {
    const float* wp = Wec + v;
    #pragma unroll 4
    for (int d = 0; d < 2 * D; d++) {
      const float w = wp[(size_t)d * VOCAB];
      #pragma unroll
      for (int bb = 0; bb < 16; bb++) acc[bb] += w * cvec[d * 16 + bb];
    }
  }

  float e[16];
  const float be = (v < VOCAB) ? bec[v] : 0.f;
  #pragma unroll
  for (int bb = 0; bb < 16; bb++)
    e[bb] = (v < VOCAB) ? __expf(acc[bb] + be) : 0.f;

  if (v < VOCAB) {
    #pragma unroll
    for (int bb = 0; bb < 16; bb++) out[(size_t)bb * VOCAB + v] = e[bb];
  }

  // per-block partial sums over the 256 v's for each b
  #pragma unroll
  for (int bb = 0; bb < 16; bb++) {
    float s = e[bb];
    #pragma unroll
    for (int off = 32; off > 0; off >>= 1) s += __shfl_down(s, off, 64);
    if ((t & 63) == 0) lred[t >> 6][bb] = s;
  }
  __syncthreads();
  if (t < 16)
    partial[blockIdx.x * 16 + t] =
        lred[0][t] + lred[1][t] + lred[2][t] + lred[3][t];
}

// K4: single block: zero masked entries (duplicate-safe via atomicExch),
// subtract their exps from the sums, produce inv[b].
__global__ __launch_bounds__(256) void k_fix_inv(
    const int* __restrict__ ids, float* __restrict__ out,
    const float* __restrict__ partial, float* __restrict__ inv)
{
  const int t = threadIdx.x;
  __shared__ float corr[16];
  __shared__ float sred[256];

  if (t < 16) corr[t] = 0.f;
  __syncthreads();

  for (int i = t; i < B * S; i += 256) {
    const int id = ids[i];
    if (id > 1) {
      const int b = i / S;
      const float old = atomicExch(&out[(size_t)b * VOCAB + id], 0.f);
      atomicAdd(&corr[b], -old);
    }
  }

  // partial sums: thread t sums chunk (t>>4) of blocks for b = t&15
  float s = 0.f;
  for (int j = (t >> 4); j < GEMV_BLOCKS; j += 16) s += partial[j * 16 + (t & 15)];
  sred[t] = s;
  __syncthreads();

  if (t < 16) {
    float tot = 0.f;
    #pragma unroll
    for (int c = 0; c < 16; c++) tot += sred[c * 16 + t];
    inv[t] = 1.0f / (tot + corr[t]);
  }
}

// K5: scale in place, float4.
__global__ __launch_bounds__(256) void k_norm(float* __restrict__ out,
                                              const float* __restrict__ inv)
{
  const int b  = blockIdx.y;
  const int i4 = blockIdx.x * 256 + threadIdx.x;
  const float iv = inv[b];
  if (i4 < VOCAB / 4) {
    float4* p = (float4*)out + (size_t)b * (VOCAB / 4) + i4;
    float4 q = *p;
    q.x *= iv; q.y *= iv; q.z *= iv; q.w *= iv;
    *p = q;
  }
}

extern "C" void kernel_launch(void* const* d_in, const int* in_sizes, int n_in,
                              void* d_out, int out_size, void* d_ws, size_t ws_size,
                              hipStream_t stream)
{
  const float* x   = (const float*)d_in[0];
  const int*   ids = (const int*)d_in[1];
  const float* Wq  = (const float*)d_in[2];
  const float* bq  = (const float*)d_in[3];
  const float* Wk  = (const float*)d_in[4];
  const float* bk  = (const float*)d_in[5];
  const float* Wv  = (const float*)d_in[6];
  const float* bv  = (const float*)d_in[7];
  const float* Wec = (const float*)d_in[8];
  const float* bec = (const float*)d_in[9];
  float* out = (float*)d_out;
  float* ws  = (float*)d_ws;

  float* scores  = ws;            // 3200
  float* cvec    = ws + 3200;     // 4096  ([256][16])
  float* partial = ws + 7296;     // GEMV_BLOCKS*16 = 6256
  float* inv     = ws + 13552;    // 16

  k_scores <<<dim3(B * (S / SCH)), dim3(128), 0, stream>>>(x, Wq, bq, Wk, bk, Wv, bv, scores);
  k_csum   <<<dim3(B),             dim3(256), 0, stream>>>(x, scores, cvec);
  k_gemv   <<<dim3(GEMV_BLOCKS),   dim3(256), 0, stream>>>(cvec, Wec, bec, out, partial);
  k_fix_inv<<<dim3(1),             dim3(256), 0, stream>>>(ids, out, partial, inv);
  k_norm   <<<dim3((VOCAB / 4 + 255) / 256, B), dim3(256), 0, stream>>>(out, inv);
}